// Round 7
// baseline (266.235 us; speedup 1.0000x reference)
//
#include <hip/hip_runtime.h>

// One step of the c4-style VM, fully fused into a single kernel.
// Outputs (int32, concatenated): [pc, sp, bp, ax, memory(33554432), halted]
//
// r7: r6 with compile fix — nontemporal stores need a clang ext_vector_type,
//     not HIP_vector_type<int,4>.

static constexpr long long MEMN = 33554432LL;
static constexpr int NT = 256;
static constexpr int NB = 4096;
static constexpr int ITERS = 8;    // NB*NT*ITERS == MEMN/4 (int4 chunks)
static constexpr int BATCH = 4;

typedef int  v4i __attribute__((ext_vector_type(4)));

__device__ __forceinline__ long long clamp_idx(long long a) {
    return a < 0 ? 0 : (a > MEMN - 1 ? MEMN - 1 : a);
}

__device__ __forceinline__ long long rd_byte(const void* mem, int flag, long long idx) {
    long long j = clamp_idx(idx);
    if (flag == 2) return (long long)((const float*)mem)[j];
    if (flag == 1) return (long long)((const int*)mem)[j << 1];  // low word of LE int64
    return (long long)((const int*)mem)[j];
}

__device__ __forceinline__ long long rd_int(const void* mem, int flag, long long addr) {
    unsigned long long v = 0;
    #pragma unroll
    for (int k = 0; k < 8; ++k)
        v |= (unsigned long long)(unsigned int)rd_byte(mem, flag, addr + k) << (8 * k);
    return (long long)v;
}

__device__ __forceinline__ long long rd_scalar(const void* p, int flag) {
    if (flag == 2) return (long long)((const float*)p)[0];
    return (long long)((const int*)p)[0];  // low word: ok for int32 and small LE int64
}

__device__ __forceinline__ v4i patch4(v4i f, long long i, int nw, int lo, int hi,
                                      const int* s_idx, const int* s_val) {
    if (nw) {
        int base = (int)(i << 2);
        if (base + 3 >= lo && base <= hi) {
            #pragma unroll
            for (int e = 0; e < 4; ++e)
                for (int t = 0; t < nw; ++t)
                    if (s_idx[t] == base + e) f[e] = s_val[t];
        }
    }
    return f;
}

__global__ __launch_bounds__(NT) void fused_step(const void* pc_b, const void* sp_b,
                                                 const void* bp_b, const void* ax_b,
                                                 const void* mem_b, int* out) {
    __shared__ int s_flag, s_nw, s_lo, s_hi;
    __shared__ int s_idx[8], s_val[8];

    const int* mi = (const int*)mem_b;

    // ---- wave 0: classify layout; lane 0: VM step ----
    if (threadIdx.x < 64) {
        unsigned int w = (unsigned int)mi[threadIdx.x];
        unsigned long long big    = __ballot(w > 255u);
        unsigned long long oddnz  = __ballot(((threadIdx.x & 1) != 0) && (w != 0u));
        if (threadIdx.x == 0) {
            int flag = big ? 2 : (oddnz ? 0 : 1);
            s_flag = flag;

            long long pc = rd_scalar(pc_b, flag);
            long long sp = rd_scalar(sp_b, flag);
            long long bp = rd_scalar(bp_b, flag);
            long long ax = rd_scalar(ax_b, flag);

            long long ins       = rd_int(mem_b, flag, pc);
            long long opcode    = ins & 255;
            long long imm       = ins >> 8;
            long long stack_top = rd_int(mem_b, flag, sp);
            long long mem_at_ax = rd_int(mem_b, flag, ax);
            long long ret_pc    = rd_int(mem_b, flag, bp + 8);
            long long bp_stack  = rd_int(mem_b, flag, bp);
            long long pc8       = (long long)((unsigned long long)pc + 8ULL);

            unsigned long long ust = (unsigned long long)stack_top;
            unsigned long long uax = (unsigned long long)ax;
            long long ax_safe = (ax == 0) ? 1LL : ax;
            long long q, r;
            if (ax_safe == -1LL) { q = (long long)(0ULL - ust); r = 0; }
            else {
                q = stack_top / ax_safe; r = stack_top % ax_safe;
                if (r != 0 && ((r < 0) != (ax_safe < 0))) { q -= 1; r += ax_safe; }
            }
            int sh = (int)(ax & 63);

            long long op = opcode > 38 ? 38 : opcode;
            long long npc = pc8, nsp = sp, nbp = bp, nax = ax;
            switch ((int)op) {
                case 0:  nax = (long long)((unsigned long long)bp + (unsigned long long)imm); break;
                case 1:  nax = imm; break;
                case 2:  npc = imm; break;
                case 3:  npc = imm; nsp = sp - 8; break;
                case 4:  npc = (ax == 0) ? imm : pc8; break;
                case 5:  npc = (ax != 0) ? imm : pc8; break;
                case 6:  nsp = sp - 8 - imm; nbp = sp - 8; break;
                case 7:  nsp = sp + imm; break;
                case 8:  npc = ret_pc; nsp = bp + 16; nbp = bp_stack; break;
                case 9:  nax = mem_at_ax; break;
                case 10: nax = mem_at_ax & 255; break;
                case 11: nsp = sp + 8; break;
                case 12: nsp = sp + 8; break;
                case 13: nsp = sp - 8; break;
                case 14: nsp = sp + 8; nax = (long long)(ust + uax); break;
                case 15: nsp = sp + 8; nax = (long long)(ust - uax); break;
                case 16: nsp = sp + 8; nax = (long long)(ust * uax); break;
                case 17: nsp = sp + 8; nax = q; break;
                case 18: nsp = sp + 8; nax = r; break;
                case 19: nsp = sp + 8; nax = stack_top | ax; break;
                case 20: nsp = sp + 8; nax = stack_top ^ ax; break;
                case 21: nsp = sp + 8; nax = stack_top & ax; break;
                case 22: nsp = sp + 8; nax = (long long)(ust << sh); break;
                case 23: nsp = sp + 8; nax = stack_top >> sh; break;
                case 24: nsp = sp + 8; nax = (stack_top == ax) ? 1 : 0; break;
                case 25: nsp = sp + 8; nax = (stack_top != ax) ? 1 : 0; break;
                case 26: nsp = sp + 8; nax = (stack_top <  ax) ? 1 : 0; break;
                case 27: nsp = sp + 8; nax = (stack_top >  ax) ? 1 : 0; break;
                case 28: nsp = sp + 8; nax = (stack_top <= ax) ? 1 : 0; break;
                case 29: nsp = sp + 8; nax = (stack_top >= ax) ? 1 : 0; break;
                case 38: npc = pc; break;
                default: nax = 0; break;
            }

            // byte-write descriptors (opcodes are mutually exclusive -> one range)
            int nw = 0, lo = 0x7fffffff, hi = -1;
            long long waddr = 0; unsigned long long wval = 0; int wbytes = 0;
            if (opcode == 13 || opcode == 3 || opcode == 6) {
                waddr = sp - 8;
                wval = (unsigned long long)(opcode == 13 ? ax : (opcode == 3 ? pc8 : bp));
                wbytes = 8;
            } else if (opcode == 11) {
                waddr = stack_top; wval = (unsigned long long)ax; wbytes = 8;
            } else if (opcode == 12) {
                waddr = stack_top; wval = (unsigned long long)(ax & 255); wbytes = 1;
            }
            for (int k = 0; k < wbytes; ++k) {
                int j = (int)clamp_idx(waddr + k);
                s_idx[nw] = j;
                s_val[nw] = (int)((wval >> (8 * k)) & 255ULL);
                lo = j < lo ? j : lo;
                hi = j > hi ? j : hi;
                ++nw;
            }
            s_nw = nw; s_lo = lo; s_hi = hi;

            if (blockIdx.x == 0) {
                out[0] = (int)npc;
                out[1] = (int)nsp;
                out[2] = (int)nbp;
                out[3] = (int)nax;
                out[4 + MEMN] = (opcode == 38) ? 1 : 0;
            }
        }
    }
    __syncthreads();

    const int  flag = s_flag;
    const int  nw   = s_nw;
    const int  lo   = s_lo;
    const int  hi   = s_hi;
    const long long tid = (long long)blockIdx.x * NT + threadIdx.x;
    const long long TOT = (long long)NB * NT;
    v4i* o = (v4i*)(out + 4);   // 16B-aligned

    if (flag == 1) {
        const v4i* m = (const v4i*)mem_b;
        #pragma unroll
        for (int g = 0; g < ITERS / BATCH; ++g) {
            v4i a[BATCH], b[BATCH];
            #pragma unroll
            for (int k = 0; k < BATCH; ++k) {
                long long i = tid + (long long)(g * BATCH + k) * TOT;
                a[k] = m[2 * i];
                b[k] = m[2 * i + 1];
            }
            #pragma unroll
            for (int k = 0; k < BATCH; ++k) {
                long long i = tid + (long long)(g * BATCH + k) * TOT;
                v4i f; f[0] = a[k][0]; f[1] = a[k][2]; f[2] = b[k][0]; f[3] = b[k][2];
                f = patch4(f, i, nw, lo, hi, s_idx, s_val);
                __builtin_nontemporal_store(f, &o[i]);
            }
        }
    } else if (flag == 0) {
        const v4i* m = (const v4i*)mem_b;
        #pragma unroll
        for (int g = 0; g < ITERS / BATCH; ++g) {
            v4i a[BATCH];
            #pragma unroll
            for (int k = 0; k < BATCH; ++k) {
                long long i = tid + (long long)(g * BATCH + k) * TOT;
                a[k] = m[i];
            }
            #pragma unroll
            for (int k = 0; k < BATCH; ++k) {
                long long i = tid + (long long)(g * BATCH + k) * TOT;
                v4i f = patch4(a[k], i, nw, lo, hi, s_idx, s_val);
                __builtin_nontemporal_store(f, &o[i]);
            }
        }
    } else {
        typedef float v4f __attribute__((ext_vector_type(4)));
        const v4f* m = (const v4f*)mem_b;
        #pragma unroll
        for (int g = 0; g < ITERS / BATCH; ++g) {
            v4f a[BATCH];
            #pragma unroll
            for (int k = 0; k < BATCH; ++k) {
                long long i = tid + (long long)(g * BATCH + k) * TOT;
                a[k] = m[i];
            }
            #pragma unroll
            for (int k = 0; k < BATCH; ++k) {
                long long i = tid + (long long)(g * BATCH + k) * TOT;
                v4i f; f[0] = (int)a[k][0]; f[1] = (int)a[k][1]; f[2] = (int)a[k][2]; f[3] = (int)a[k][3];
                f = patch4(f, i, nw, lo, hi, s_idx, s_val);
                __builtin_nontemporal_store(f, &o[i]);
            }
        }
    }
}

extern "C" void kernel_launch(void* const* d_in, const int* in_sizes, int n_in,
                              void* d_out, int out_size, void* d_ws, size_t ws_size,
                              hipStream_t stream) {
    int* out = (int*)d_out;
    fused_step<<<NB, NT, 0, stream>>>(d_in[0], d_in[1], d_in[2], d_in[3], d_in[4], out);
}

// Round 9
// 255.754 us; speedup vs baseline: 1.0410x; 1.0410x over previous
//
#include <hip/hip_runtime.h>

// One step of the c4-style VM, fully fused into a single kernel.
// Outputs (int32, concatenated): [pc, sp, bp, ax, memory(33554432), halted]
//
// r8: force MLP — 8 named loads per group, sched_barrier(0) between the
//     load cluster and the use cluster so the compiler cannot sink loads
//     back to their uses (r7 lesson: VGPR stayed 24 => batch was undone).
//     Plain stores (r7 lesson: nontemporal stores regressed 20%).

static constexpr long long MEMN = 33554432LL;
static constexpr int NT = 256;
static constexpr int NB = 4096;
static constexpr int ITERS = 8;    // NB*NT*ITERS == MEMN/4 (int4 chunks)
static constexpr int BATCH = 4;

typedef int   v4i __attribute__((ext_vector_type(4)));
typedef float v4f __attribute__((ext_vector_type(4)));

__device__ __forceinline__ long long clamp_idx(long long a) {
    return a < 0 ? 0 : (a > MEMN - 1 ? MEMN - 1 : a);
}

__device__ __forceinline__ long long rd_byte(const void* mem, int flag, long long idx) {
    long long j = clamp_idx(idx);
    if (flag == 2) return (long long)((const float*)mem)[j];
    if (flag == 1) return (long long)((const int*)mem)[j << 1];  // low word of LE int64
    return (long long)((const int*)mem)[j];
}

__device__ __forceinline__ long long rd_int(const void* mem, int flag, long long addr) {
    unsigned long long v = 0;
    #pragma unroll
    for (int k = 0; k < 8; ++k)
        v |= (unsigned long long)(unsigned int)rd_byte(mem, flag, addr + k) << (8 * k);
    return (long long)v;
}

__device__ __forceinline__ long long rd_scalar(const void* p, int flag) {
    if (flag == 2) return (long long)((const float*)p)[0];
    return (long long)((const int*)p)[0];  // low word: ok for int32 and small LE int64
}

__device__ __forceinline__ v4i patch4(v4i f, long long i, int nw, int lo, int hi,
                                      const int* s_idx, const int* s_val) {
    if (nw) {
        int base = (int)(i << 2);
        if (base + 3 >= lo && base <= hi) {
            #pragma unroll
            for (int e = 0; e < 4; ++e)
                for (int t = 0; t < nw; ++t)
                    if (s_idx[t] == base + e) f[e] = s_val[t];
        }
    }
    return f;
}

__global__ __launch_bounds__(NT) void fused_step(const void* pc_b, const void* sp_b,
                                                 const void* bp_b, const void* ax_b,
                                                 const void* mem_b, int* out) {
    __shared__ int s_flag, s_nw, s_lo, s_hi;
    __shared__ int s_idx[8], s_val[8];

    const int* mi = (const int*)mem_b;

    // ---- wave 0: classify layout; lane 0: VM step ----
    if (threadIdx.x < 64) {
        unsigned int w = (unsigned int)mi[threadIdx.x];
        unsigned long long big    = __ballot(w > 255u);
        unsigned long long oddnz  = __ballot(((threadIdx.x & 1) != 0) && (w != 0u));
        if (threadIdx.x == 0) {
            int flag = big ? 2 : (oddnz ? 0 : 1);
            s_flag = flag;

            long long pc = rd_scalar(pc_b, flag);
            long long sp = rd_scalar(sp_b, flag);
            long long bp = rd_scalar(bp_b, flag);
            long long ax = rd_scalar(ax_b, flag);

            long long ins       = rd_int(mem_b, flag, pc);
            long long opcode    = ins & 255;
            long long imm       = ins >> 8;
            long long stack_top = rd_int(mem_b, flag, sp);
            long long mem_at_ax = rd_int(mem_b, flag, ax);
            long long ret_pc    = rd_int(mem_b, flag, bp + 8);
            long long bp_stack  = rd_int(mem_b, flag, bp);
            long long pc8       = (long long)((unsigned long long)pc + 8ULL);

            unsigned long long ust = (unsigned long long)stack_top;
            unsigned long long uax = (unsigned long long)ax;
            long long ax_safe = (ax == 0) ? 1LL : ax;
            long long q, r;
            if (ax_safe == -1LL) { q = (long long)(0ULL - ust); r = 0; }
            else {
                q = stack_top / ax_safe; r = stack_top % ax_safe;
                if (r != 0 && ((r < 0) != (ax_safe < 0))) { q -= 1; r += ax_safe; }
            }
            int sh = (int)(ax & 63);

            long long op = opcode > 38 ? 38 : opcode;
            long long npc = pc8, nsp = sp, nbp = bp, nax = ax;
            switch ((int)op) {
                case 0:  nax = (long long)((unsigned long long)bp + (unsigned long long)imm); break;
                case 1:  nax = imm; break;
                case 2:  npc = imm; break;
                case 3:  npc = imm; nsp = sp - 8; break;
                case 4:  npc = (ax == 0) ? imm : pc8; break;
                case 5:  npc = (ax != 0) ? imm : pc8; break;
                case 6:  nsp = sp - 8 - imm; nbp = sp - 8; break;
                case 7:  nsp = sp + imm; break;
                case 8:  npc = ret_pc; nsp = bp + 16; nbp = bp_stack; break;
                case 9:  nax = mem_at_ax; break;
                case 10: nax = mem_at_ax & 255; break;
                case 11: nsp = sp + 8; break;
                case 12: nsp = sp + 8; break;
                case 13: nsp = sp - 8; break;
                case 14: nsp = sp + 8; nax = (long long)(ust + uax); break;
                case 15: nsp = sp + 8; nax = (long long)(ust - uax); break;
                case 16: nsp = sp + 8; nax = (long long)(ust * uax); break;
                case 17: nsp = sp + 8; nax = q; break;
                case 18: nsp = sp + 8; nax = r; break;
                case 19: nsp = sp + 8; nax = stack_top | ax; break;
                case 20: nsp = sp + 8; nax = stack_top ^ ax; break;
                case 21: nsp = sp + 8; nax = stack_top & ax; break;
                case 22: nsp = sp + 8; nax = (long long)(ust << sh); break;
                case 23: nsp = sp + 8; nax = stack_top >> sh; break;
                case 24: nsp = sp + 8; nax = (stack_top == ax) ? 1 : 0; break;
                case 25: nsp = sp + 8; nax = (stack_top != ax) ? 1 : 0; break;
                case 26: nsp = sp + 8; nax = (stack_top <  ax) ? 1 : 0; break;
                case 27: nsp = sp + 8; nax = (stack_top >  ax) ? 1 : 0; break;
                case 28: nsp = sp + 8; nax = (stack_top <= ax) ? 1 : 0; break;
                case 29: nsp = sp + 8; nax = (stack_top >= ax) ? 1 : 0; break;
                case 38: npc = pc; break;
                default: nax = 0; break;
            }

            // byte-write descriptors (opcodes are mutually exclusive -> one range)
            int nw = 0, lo = 0x7fffffff, hi = -1;
            long long waddr = 0; unsigned long long wval = 0; int wbytes = 0;
            if (opcode == 13 || opcode == 3 || opcode == 6) {
                waddr = sp - 8;
                wval = (unsigned long long)(opcode == 13 ? ax : (opcode == 3 ? pc8 : bp));
                wbytes = 8;
            } else if (opcode == 11) {
                waddr = stack_top; wval = (unsigned long long)ax; wbytes = 8;
            } else if (opcode == 12) {
                waddr = stack_top; wval = (unsigned long long)(ax & 255); wbytes = 1;
            }
            for (int k = 0; k < wbytes; ++k) {
                int j = (int)clamp_idx(waddr + k);
                s_idx[nw] = j;
                s_val[nw] = (int)((wval >> (8 * k)) & 255ULL);
                lo = j < lo ? j : lo;
                hi = j > hi ? j : hi;
                ++nw;
            }
            s_nw = nw; s_lo = lo; s_hi = hi;

            if (blockIdx.x == 0) {
                out[0] = (int)npc;
                out[1] = (int)nsp;
                out[2] = (int)nbp;
                out[3] = (int)nax;
                out[4 + MEMN] = (opcode == 38) ? 1 : 0;
            }
        }
    }
    __syncthreads();

    const int  flag = s_flag;
    const int  nw   = s_nw;
    const int  lo   = s_lo;
    const int  hi   = s_hi;
    const long long tid = (long long)blockIdx.x * NT + threadIdx.x;
    const long long TOT = (long long)NB * NT;
    v4i* o = (v4i*)(out + 4);   // 16B-aligned

    if (flag == 1) {
        const v4i* m = (const v4i*)mem_b;
        #pragma unroll
        for (int g = 0; g < ITERS / BATCH; ++g) {
            const long long i0 = tid + (long long)(g * BATCH + 0) * TOT;
            const long long i1 = tid + (long long)(g * BATCH + 1) * TOT;
            const long long i2 = tid + (long long)(g * BATCH + 2) * TOT;
            const long long i3 = tid + (long long)(g * BATCH + 3) * TOT;
            // 8 independent loads, all issued before any use:
            v4i a0 = m[2 * i0], b0 = m[2 * i0 + 1];
            v4i a1 = m[2 * i1], b1 = m[2 * i1 + 1];
            v4i a2 = m[2 * i2], b2 = m[2 * i2 + 1];
            v4i a3 = m[2 * i3], b3 = m[2 * i3 + 1];
            __builtin_amdgcn_sched_barrier(0);
            v4i f0 = { a0[0], a0[2], b0[0], b0[2] };
            v4i f1 = { a1[0], a1[2], b1[0], b1[2] };
            v4i f2 = { a2[0], a2[2], b2[0], b2[2] };
            v4i f3 = { a3[0], a3[2], b3[0], b3[2] };
            f0 = patch4(f0, i0, nw, lo, hi, s_idx, s_val);
            f1 = patch4(f1, i1, nw, lo, hi, s_idx, s_val);
            f2 = patch4(f2, i2, nw, lo, hi, s_idx, s_val);
            f3 = patch4(f3, i3, nw, lo, hi, s_idx, s_val);
            o[i0] = f0;
            o[i1] = f1;
            o[i2] = f2;
            o[i3] = f3;
        }
    } else if (flag == 0) {
        const v4i* m = (const v4i*)mem_b;
        #pragma unroll
        for (int g = 0; g < ITERS / BATCH; ++g) {
            const long long i0 = tid + (long long)(g * BATCH + 0) * TOT;
            const long long i1 = tid + (long long)(g * BATCH + 1) * TOT;
            const long long i2 = tid + (long long)(g * BATCH + 2) * TOT;
            const long long i3 = tid + (long long)(g * BATCH + 3) * TOT;
            v4i a0 = m[i0], a1 = m[i1], a2 = m[i2], a3 = m[i3];
            __builtin_amdgcn_sched_barrier(0);
            o[i0] = patch4(a0, i0, nw, lo, hi, s_idx, s_val);
            o[i1] = patch4(a1, i1, nw, lo, hi, s_idx, s_val);
            o[i2] = patch4(a2, i2, nw, lo, hi, s_idx, s_val);
            o[i3] = patch4(a3, i3, nw, lo, hi, s_idx, s_val);
        }
    } else {
        const v4f* m = (const v4f*)mem_b;
        #pragma unroll
        for (int g = 0; g < ITERS / BATCH; ++g) {
            const long long i0 = tid + (long long)(g * BATCH + 0) * TOT;
            const long long i1 = tid + (long long)(g * BATCH + 1) * TOT;
            const long long i2 = tid + (long long)(g * BATCH + 2) * TOT;
            const long long i3 = tid + (long long)(g * BATCH + 3) * TOT;
            v4f a0 = m[i0], a1 = m[i1], a2 = m[i2], a3 = m[i3];
            __builtin_amdgcn_sched_barrier(0);
            v4i f0 = { (int)a0[0], (int)a0[1], (int)a0[2], (int)a0[3] };
            v4i f1 = { (int)a1[0], (int)a1[1], (int)a1[2], (int)a1[3] };
            v4i f2 = { (int)a2[0], (int)a2[1], (int)a2[2], (int)a2[3] };
            v4i f3 = { (int)a3[0], (int)a3[1], (int)a3[2], (int)a3[3] };
            o[i0] = patch4(f0, i0, nw, lo, hi, s_idx, s_val);
            o[i1] = patch4(f1, i1, nw, lo, hi, s_idx, s_val);
            o[i2] = patch4(f2, i2, nw, lo, hi, s_idx, s_val);
            o[i3] = patch4(f3, i3, nw, lo, hi, s_idx, s_val);
        }
    }
}

extern "C" void kernel_launch(void* const* d_in, const int* in_sizes, int n_in,
                              void* d_out, int out_size, void* d_ws, size_t ws_size,
                              hipStream_t stream) {
    int* out = (int*)d_out;
    fused_step<<<NB, NT, 0, stream>>>(d_in[0], d_in[1], d_in[2], d_in[3], d_in[4], out);
}

// Round 10
// 252.302 us; speedup vs baseline: 1.0552x; 1.0137x over previous
//
#include <hip/hip_runtime.h>

// One step of the c4-style VM, fully fused into a single kernel.
// Outputs (int32, concatenated): [pc, sp, bp, ax, memory(33554432), halted]
//
// r10: fix instruction-level coalescing on the int64 path. Previously each
// load instruction had 32B lane stride (2KB span, 32 cache lines). Now each
// wave loads two unit-stride 1KB blocks (A=[2W,2W+64), B=[2W+64,2W+128))
// and redistributes in-register with 8 __shfl + 4 selects per thread.

static constexpr long long MEMN = 33554432LL;
static constexpr int NT = 256;
static constexpr int NB = 4096;
static constexpr int ITERS = 8;    // NB*NT*ITERS == MEMN/4 (int4 chunks)

typedef int   v4i __attribute__((ext_vector_type(4)));
typedef float v4f __attribute__((ext_vector_type(4)));

__device__ __forceinline__ long long clamp_idx(long long a) {
    return a < 0 ? 0 : (a > MEMN - 1 ? MEMN - 1 : a);
}

__device__ __forceinline__ long long rd_byte(const void* mem, int flag, long long idx) {
    long long j = clamp_idx(idx);
    if (flag == 2) return (long long)((const float*)mem)[j];
    if (flag == 1) return (long long)((const int*)mem)[j << 1];  // low word of LE int64
    return (long long)((const int*)mem)[j];
}

__device__ __forceinline__ long long rd_int(const void* mem, int flag, long long addr) {
    unsigned long long v = 0;
    #pragma unroll
    for (int k = 0; k < 8; ++k)
        v |= (unsigned long long)(unsigned int)rd_byte(mem, flag, addr + k) << (8 * k);
    return (long long)v;
}

__device__ __forceinline__ long long rd_scalar(const void* p, int flag) {
    if (flag == 2) return (long long)((const float*)p)[0];
    return (long long)((const int*)p)[0];  // low word: ok for int32 and small LE int64
}

__device__ __forceinline__ v4i patch4(v4i f, long long i, int nw, int lo, int hi,
                                      const int* s_idx, const int* s_val) {
    if (nw) {
        int base = (int)(i << 2);
        if (base + 3 >= lo && base <= hi) {
            #pragma unroll
            for (int e = 0; e < 4; ++e)
                for (int t = 0; t < nw; ++t)
                    if (s_idx[t] == base + e) f[e] = s_val[t];
        }
    }
    return f;
}

__global__ __launch_bounds__(NT) void fused_step(const void* pc_b, const void* sp_b,
                                                 const void* bp_b, const void* ax_b,
                                                 const void* mem_b, int* out) {
    __shared__ int s_flag, s_nw, s_lo, s_hi;
    __shared__ int s_idx[8], s_val[8];

    const int* mi = (const int*)mem_b;

    // ---- wave 0: classify layout; lane 0: VM step ----
    if (threadIdx.x < 64) {
        unsigned int w = (unsigned int)mi[threadIdx.x];
        unsigned long long big    = __ballot(w > 255u);
        unsigned long long oddnz  = __ballot(((threadIdx.x & 1) != 0) && (w != 0u));
        if (threadIdx.x == 0) {
            int flag = big ? 2 : (oddnz ? 0 : 1);
            s_flag = flag;

            long long pc = rd_scalar(pc_b, flag);
            long long sp = rd_scalar(sp_b, flag);
            long long bp = rd_scalar(bp_b, flag);
            long long ax = rd_scalar(ax_b, flag);

            long long ins       = rd_int(mem_b, flag, pc);
            long long opcode    = ins & 255;
            long long imm       = ins >> 8;
            long long stack_top = rd_int(mem_b, flag, sp);
            long long mem_at_ax = rd_int(mem_b, flag, ax);
            long long ret_pc    = rd_int(mem_b, flag, bp + 8);
            long long bp_stack  = rd_int(mem_b, flag, bp);
            long long pc8       = (long long)((unsigned long long)pc + 8ULL);

            unsigned long long ust = (unsigned long long)stack_top;
            unsigned long long uax = (unsigned long long)ax;
            long long ax_safe = (ax == 0) ? 1LL : ax;
            long long q, r;
            if (ax_safe == -1LL) { q = (long long)(0ULL - ust); r = 0; }
            else {
                q = stack_top / ax_safe; r = stack_top % ax_safe;
                if (r != 0 && ((r < 0) != (ax_safe < 0))) { q -= 1; r += ax_safe; }
            }
            int sh = (int)(ax & 63);

            long long op = opcode > 38 ? 38 : opcode;
            long long npc = pc8, nsp = sp, nbp = bp, nax = ax;
            switch ((int)op) {
                case 0:  nax = (long long)((unsigned long long)bp + (unsigned long long)imm); break;
                case 1:  nax = imm; break;
                case 2:  npc = imm; break;
                case 3:  npc = imm; nsp = sp - 8; break;
                case 4:  npc = (ax == 0) ? imm : pc8; break;
                case 5:  npc = (ax != 0) ? imm : pc8; break;
                case 6:  nsp = sp - 8 - imm; nbp = sp - 8; break;
                case 7:  nsp = sp + imm; break;
                case 8:  npc = ret_pc; nsp = bp + 16; nbp = bp_stack; break;
                case 9:  nax = mem_at_ax; break;
                case 10: nax = mem_at_ax & 255; break;
                case 11: nsp = sp + 8; break;
                case 12: nsp = sp + 8; break;
                case 13: nsp = sp - 8; break;
                case 14: nsp = sp + 8; nax = (long long)(ust + uax); break;
                case 15: nsp = sp + 8; nax = (long long)(ust - uax); break;
                case 16: nsp = sp + 8; nax = (long long)(ust * uax); break;
                case 17: nsp = sp + 8; nax = q; break;
                case 18: nsp = sp + 8; nax = r; break;
                case 19: nsp = sp + 8; nax = stack_top | ax; break;
                case 20: nsp = sp + 8; nax = stack_top ^ ax; break;
                case 21: nsp = sp + 8; nax = stack_top & ax; break;
                case 22: nsp = sp + 8; nax = (long long)(ust << sh); break;
                case 23: nsp = sp + 8; nax = stack_top >> sh; break;
                case 24: nsp = sp + 8; nax = (stack_top == ax) ? 1 : 0; break;
                case 25: nsp = sp + 8; nax = (stack_top != ax) ? 1 : 0; break;
                case 26: nsp = sp + 8; nax = (stack_top <  ax) ? 1 : 0; break;
                case 27: nsp = sp + 8; nax = (stack_top >  ax) ? 1 : 0; break;
                case 28: nsp = sp + 8; nax = (stack_top <= ax) ? 1 : 0; break;
                case 29: nsp = sp + 8; nax = (stack_top >= ax) ? 1 : 0; break;
                case 38: npc = pc; break;
                default: nax = 0; break;
            }

            // byte-write descriptors (opcodes are mutually exclusive -> one range)
            int nw = 0, lo = 0x7fffffff, hi = -1;
            long long waddr = 0; unsigned long long wval = 0; int wbytes = 0;
            if (opcode == 13 || opcode == 3 || opcode == 6) {
                waddr = sp - 8;
                wval = (unsigned long long)(opcode == 13 ? ax : (opcode == 3 ? pc8 : bp));
                wbytes = 8;
            } else if (opcode == 11) {
                waddr = stack_top; wval = (unsigned long long)ax; wbytes = 8;
            } else if (opcode == 12) {
                waddr = stack_top; wval = (unsigned long long)(ax & 255); wbytes = 1;
            }
            for (int k = 0; k < wbytes; ++k) {
                int j = (int)clamp_idx(waddr + k);
                s_idx[nw] = j;
                s_val[nw] = (int)((wval >> (8 * k)) & 255ULL);
                lo = j < lo ? j : lo;
                hi = j > hi ? j : hi;
                ++nw;
            }
            s_nw = nw; s_lo = lo; s_hi = hi;

            if (blockIdx.x == 0) {
                out[0] = (int)npc;
                out[1] = (int)nsp;
                out[2] = (int)nbp;
                out[3] = (int)nax;
                out[4 + MEMN] = (opcode == 38) ? 1 : 0;
            }
        }
    }
    __syncthreads();

    const int  flag = s_flag;
    const int  nw   = s_nw;
    const int  lo   = s_lo;
    const int  hi   = s_hi;
    v4i* o = (v4i*)(out + 4);   // 16B-aligned

    if (flag == 1) {
        const v4i* m = (const v4i*)mem_b;
        const int lane = threadIdx.x & 63;
        const long long gw = (long long)((blockIdx.x * NT + threadIdx.x) >> 6); // global wave id
        const long long NW = (long long)NB * NT / 64;                           // total waves
        const int slX = (2 * lane) & 63;
        const int slY = (2 * lane + 1) & 63;
        const bool loA = lane < 32;
        #pragma unroll
        for (int k = 0; k < ITERS; ++k) {
            const long long W = (gw + (long long)k * NW) << 6;  // wave's output-chunk base
            // unit-stride loads: A covers input chunks [2W,2W+64), B covers [2W+64,2W+128)
            v4i A = m[2 * W + lane];
            v4i B = m[2 * W + 64 + lane];
            // redistribute: out chunk W+l needs X=chunk(2W+2l) dwords{0,2}, Y=chunk(2W+2l+1) dwords{0,2}
            int a0 = __shfl(A[0], slX, 64), b0 = __shfl(B[0], slX, 64);
            int a2 = __shfl(A[2], slX, 64), b2 = __shfl(B[2], slX, 64);
            int c0 = __shfl(A[0], slY, 64), d0 = __shfl(B[0], slY, 64);
            int c2 = __shfl(A[2], slY, 64), d2 = __shfl(B[2], slY, 64);
            v4i f;
            f[0] = loA ? a0 : b0;
            f[1] = loA ? a2 : b2;
            f[2] = loA ? c0 : d0;
            f[3] = loA ? c2 : d2;
            const long long i = W + lane;
            f = patch4(f, i, nw, lo, hi, s_idx, s_val);
            o[i] = f;
        }
    } else if (flag == 0) {
        const v4i* m = (const v4i*)mem_b;
        const long long tid = (long long)blockIdx.x * NT + threadIdx.x;
        const long long TOT = (long long)NB * NT;
        #pragma unroll
        for (int k = 0; k < ITERS; ++k) {
            long long i = tid + (long long)k * TOT;
            v4i f = m[i];
            f = patch4(f, i, nw, lo, hi, s_idx, s_val);
            o[i] = f;
        }
    } else {
        const v4f* m = (const v4f*)mem_b;
        const long long tid = (long long)blockIdx.x * NT + threadIdx.x;
        const long long TOT = (long long)NB * NT;
        #pragma unroll
        for (int k = 0; k < ITERS; ++k) {
            long long i = tid + (long long)k * TOT;
            v4f a = m[i];
            v4i f; f[0] = (int)a[0]; f[1] = (int)a[1]; f[2] = (int)a[2]; f[3] = (int)a[3];
            f = patch4(f, i, nw, lo, hi, s_idx, s_val);
            o[i] = f;
        }
    }
}

extern "C" void kernel_launch(void* const* d_in, const int* in_sizes, int n_in,
                              void* d_out, int out_size, void* d_ws, size_t ws_size,
                              hipStream_t stream) {
    int* out = (int*)d_out;
    fused_step<<<NB, NT, 0, stream>>>(d_in[0], d_in[1], d_in[2], d_in[3], d_in[4], out);
}

// Round 11
// 250.324 us; speedup vs baseline: 1.0636x; 1.0079x over previous
//
#include <hip/hip_runtime.h>

// One step of the c4-style VM, fully fused into a single kernel.
// Outputs (int32, concatenated): [pc, sp, bp, ax, memory(33554432), halted]
//
// r11: revert copy loop to the empirically fastest structure (r2's copy_mem:
// 2048 blocks, runtime grid-stride, plain 2-loads-per-chunk). All r6-r10
// interventions (nt stores, named batches, sched_barrier, shfl redistribute)
// measured neutral-to-negative; the memory pipe is the limiter.

static constexpr long long MEMN = 33554432LL;
static constexpr int NT = 256;
static constexpr int NB = 2048;

typedef int   v4i __attribute__((ext_vector_type(4)));
typedef float v4f __attribute__((ext_vector_type(4)));

__device__ __forceinline__ long long clamp_idx(long long a) {
    return a < 0 ? 0 : (a > MEMN - 1 ? MEMN - 1 : a);
}

__device__ __forceinline__ long long rd_byte(const void* mem, int flag, long long idx) {
    long long j = clamp_idx(idx);
    if (flag == 2) return (long long)((const float*)mem)[j];
    if (flag == 1) return (long long)((const int*)mem)[j << 1];  // low word of LE int64
    return (long long)((const int*)mem)[j];
}

__device__ __forceinline__ long long rd_int(const void* mem, int flag, long long addr) {
    unsigned long long v = 0;
    #pragma unroll
    for (int k = 0; k < 8; ++k)
        v |= (unsigned long long)(unsigned int)rd_byte(mem, flag, addr + k) << (8 * k);
    return (long long)v;
}

__device__ __forceinline__ long long rd_scalar(const void* p, int flag) {
    if (flag == 2) return (long long)((const float*)p)[0];
    return (long long)((const int*)p)[0];  // low word: ok for int32 and small LE int64
}

__device__ __forceinline__ v4i patch4(v4i f, long long i, int nw, int lo, int hi,
                                      const int* s_idx, const int* s_val) {
    if (nw) {
        int base = (int)(i << 2);
        if (base + 3 >= lo && base <= hi) {
            #pragma unroll
            for (int e = 0; e < 4; ++e)
                for (int t = 0; t < nw; ++t)
                    if (s_idx[t] == base + e) f[e] = s_val[t];
        }
    }
    return f;
}

__global__ __launch_bounds__(NT) void fused_step(const void* pc_b, const void* sp_b,
                                                 const void* bp_b, const void* ax_b,
                                                 const void* mem_b, int* out) {
    __shared__ int s_flag, s_nw, s_lo, s_hi;
    __shared__ int s_idx[8], s_val[8];

    const int* mi = (const int*)mem_b;

    // ---- wave 0: classify layout; lane 0: VM step ----
    if (threadIdx.x < 64) {
        unsigned int w = (unsigned int)mi[threadIdx.x];
        unsigned long long big    = __ballot(w > 255u);
        unsigned long long oddnz  = __ballot(((threadIdx.x & 1) != 0) && (w != 0u));
        if (threadIdx.x == 0) {
            int flag = big ? 2 : (oddnz ? 0 : 1);
            s_flag = flag;

            long long pc = rd_scalar(pc_b, flag);
            long long sp = rd_scalar(sp_b, flag);
            long long bp = rd_scalar(bp_b, flag);
            long long ax = rd_scalar(ax_b, flag);

            long long ins       = rd_int(mem_b, flag, pc);
            long long opcode    = ins & 255;
            long long imm       = ins >> 8;
            long long stack_top = rd_int(mem_b, flag, sp);
            long long mem_at_ax = rd_int(mem_b, flag, ax);
            long long ret_pc    = rd_int(mem_b, flag, bp + 8);
            long long bp_stack  = rd_int(mem_b, flag, bp);
            long long pc8       = (long long)((unsigned long long)pc + 8ULL);

            unsigned long long ust = (unsigned long long)stack_top;
            unsigned long long uax = (unsigned long long)ax;
            long long ax_safe = (ax == 0) ? 1LL : ax;
            long long q, r;
            if (ax_safe == -1LL) { q = (long long)(0ULL - ust); r = 0; }
            else {
                q = stack_top / ax_safe; r = stack_top % ax_safe;
                if (r != 0 && ((r < 0) != (ax_safe < 0))) { q -= 1; r += ax_safe; }
            }
            int sh = (int)(ax & 63);

            long long op = opcode > 38 ? 38 : opcode;
            long long npc = pc8, nsp = sp, nbp = bp, nax = ax;
            switch ((int)op) {
                case 0:  nax = (long long)((unsigned long long)bp + (unsigned long long)imm); break;
                case 1:  nax = imm; break;
                case 2:  npc = imm; break;
                case 3:  npc = imm; nsp = sp - 8; break;
                case 4:  npc = (ax == 0) ? imm : pc8; break;
                case 5:  npc = (ax != 0) ? imm : pc8; break;
                case 6:  nsp = sp - 8 - imm; nbp = sp - 8; break;
                case 7:  nsp = sp + imm; break;
                case 8:  npc = ret_pc; nsp = bp + 16; nbp = bp_stack; break;
                case 9:  nax = mem_at_ax; break;
                case 10: nax = mem_at_ax & 255; break;
                case 11: nsp = sp + 8; break;
                case 12: nsp = sp + 8; break;
                case 13: nsp = sp - 8; break;
                case 14: nsp = sp + 8; nax = (long long)(ust + uax); break;
                case 15: nsp = sp + 8; nax = (long long)(ust - uax); break;
                case 16: nsp = sp + 8; nax = (long long)(ust * uax); break;
                case 17: nsp = sp + 8; nax = q; break;
                case 18: nsp = sp + 8; nax = r; break;
                case 19: nsp = sp + 8; nax = stack_top | ax; break;
                case 20: nsp = sp + 8; nax = stack_top ^ ax; break;
                case 21: nsp = sp + 8; nax = stack_top & ax; break;
                case 22: nsp = sp + 8; nax = (long long)(ust << sh); break;
                case 23: nsp = sp + 8; nax = stack_top >> sh; break;
                case 24: nsp = sp + 8; nax = (stack_top == ax) ? 1 : 0; break;
                case 25: nsp = sp + 8; nax = (stack_top != ax) ? 1 : 0; break;
                case 26: nsp = sp + 8; nax = (stack_top <  ax) ? 1 : 0; break;
                case 27: nsp = sp + 8; nax = (stack_top >  ax) ? 1 : 0; break;
                case 28: nsp = sp + 8; nax = (stack_top <= ax) ? 1 : 0; break;
                case 29: nsp = sp + 8; nax = (stack_top >= ax) ? 1 : 0; break;
                case 38: npc = pc; break;
                default: nax = 0; break;
            }

            // byte-write descriptors (opcodes are mutually exclusive -> one range)
            int nw = 0, lo = 0x7fffffff, hi = -1;
            long long waddr = 0; unsigned long long wval = 0; int wbytes = 0;
            if (opcode == 13 || opcode == 3 || opcode == 6) {
                waddr = sp - 8;
                wval = (unsigned long long)(opcode == 13 ? ax : (opcode == 3 ? pc8 : bp));
                wbytes = 8;
            } else if (opcode == 11) {
                waddr = stack_top; wval = (unsigned long long)ax; wbytes = 8;
            } else if (opcode == 12) {
                waddr = stack_top; wval = (unsigned long long)(ax & 255); wbytes = 1;
            }
            for (int k = 0; k < wbytes; ++k) {
                int j = (int)clamp_idx(waddr + k);
                s_idx[nw] = j;
                s_val[nw] = (int)((wval >> (8 * k)) & 255ULL);
                lo = j < lo ? j : lo;
                hi = j > hi ? j : hi;
                ++nw;
            }
            s_nw = nw; s_lo = lo; s_hi = hi;

            if (blockIdx.x == 0) {
                out[0] = (int)npc;
                out[1] = (int)nsp;
                out[2] = (int)nbp;
                out[3] = (int)nax;
                out[4 + MEMN] = (opcode == 38) ? 1 : 0;
            }
        }
    }
    __syncthreads();

    const int  flag = s_flag;
    const int  nw   = s_nw;
    const int  lo   = s_lo;
    const int  hi   = s_hi;
    const long long tid    = (long long)blockIdx.x * NT + threadIdx.x;
    const long long stride = (long long)NB * NT;
    const long long nvec   = MEMN / 4;
    v4i* o = (v4i*)(out + 4);   // 16B-aligned

    if (flag == 1) {
        const v4i* m = (const v4i*)mem_b;
        for (long long i = tid; i < nvec; i += stride) {
            v4i a = m[2 * i];
            v4i b = m[2 * i + 1];
            v4i f; f[0] = a[0]; f[1] = a[2]; f[2] = b[0]; f[3] = b[2];
            f = patch4(f, i, nw, lo, hi, s_idx, s_val);
            o[i] = f;
        }
    } else if (flag == 0) {
        const v4i* m = (const v4i*)mem_b;
        for (long long i = tid; i < nvec; i += stride) {
            v4i f = patch4(m[i], i, nw, lo, hi, s_idx, s_val);
            o[i] = f;
        }
    } else {
        const v4f* m = (const v4f*)mem_b;
        for (long long i = tid; i < nvec; i += stride) {
            v4f a = m[i];
            v4i f; f[0] = (int)a[0]; f[1] = (int)a[1]; f[2] = (int)a[2]; f[3] = (int)a[3];
            f = patch4(f, i, nw, lo, hi, s_idx, s_val);
            o[i] = f;
        }
    }
}

extern "C" void kernel_launch(void* const* d_in, const int* in_sizes, int n_in,
                              void* d_out, int out_size, void* d_ws, size_t ws_size,
                              hipStream_t stream) {
    int* out = (int*)d_out;
    fused_step<<<NB, NT, 0, stream>>>(d_in[0], d_in[1], d_in[2], d_in[3], d_in[4], out);
}